// Round 9
// baseline (669.992 us; speedup 1.0000x reference)
//
#include <hip/hip_runtime.h>
#include <hip/hip_bf16.h>
#include <math.h>

// WindowAttention: B=2048, C=256, H=8, d_k=32, wh=ww=7 -> L=49, nW=64.
// Reference reassigns v = k. Outputs: score (2048*256*49) then attn
// (2048*8*49*49), fp32, concatenated in d_out.
//
// MFMA design, R9: R8 body (2 waves per (b,h), K1-sharing via LDS, P hi/lo
// planes, lgkm-only barriers, no-max softmax, HW bf16 cvt) wrapped in an
// h-LOOP: grid 2048 blocks, each block processes b=blockIdx.x, h=0..7.
//
// Rationale (R5-R8 counter pattern): dur pinned at 177-200us across 23-52%
// occupancy with ALL pipes <30% busy and wave lifetime >> critical path ->
// shared front-end resource suspected: each wave streamed ~20KB of unique
// fully-unrolled code once (zero reuse), plus block launch churn. The loop
// body is fetched once and stays I$-hot for 8 iters; launches drop 8x;
// maskF[w] becomes L1-resident across iters.
//
// Also: exp2-fold (prep pre-multiplies bias+mask by log2e, scale absorbs
// log2e, softmax uses native exp2f) -- exact transform.
//
// Spill discipline (R2-R4 counter-proven): WRITE_SIZE >> 256MB = spill
// tripwire. Loop adds ~4 VGPRs only.

#define LW 49
#define NH 8

typedef short s16x8 __attribute__((ext_vector_type(8)));
typedef float f32x4 __attribute__((ext_vector_type(4)));

union Frag { s16x8 v; unsigned short u[8]; };

__device__ __forceinline__ unsigned short f2bf(float x) {
    return __builtin_bit_cast(unsigned short, __float2bfloat16(x));
}
__device__ __forceinline__ float bf2f(unsigned short h) {
    return __uint_as_float(((unsigned)h) << 16);
}
// hi = bf16(x); lo = bf16(x - hi). 3-pass MFMA (Ah*Bh + Al*Bh + Ah*Bl)
// gives ~fp32 accuracy.
__device__ __forceinline__ void split8(const float* xf, Frag& hi, Frag& lo) {
    #pragma unroll
    for (int j = 0; j < 8; j++) {
        const unsigned short hb = f2bf(xf[j]);
        hi.u[j] = hb;
        lo.u[j] = f2bf(xf[j] - bf2f(hb));
    }
}

// LDS-only barrier: does NOT drain vmcnt (global loads/stores keep flying).
__device__ __forceinline__ void lds_barrier() {
    asm volatile("s_waitcnt lgkmcnt(0)" ::: "memory");
    __builtin_amdgcn_s_barrier();
    asm volatile("" ::: "memory");
    __builtin_amdgcn_sched_barrier(0);
}

#define MFMA16(A, B, C) __builtin_amdgcn_mfma_f32_16x16x32_bf16((A), (B), (C), 0, 0, 0)

// ---------------- prep: bias & mask expanded into C-fragment order ----------
// Values pre-multiplied by log2(e) so the kernel can use native exp2.
__global__ __launch_bounds__(256) void prep_frag_kernel(
    const float* __restrict__ mask, const float* __restrict__ table,
    const int* __restrict__ idx,
    float* __restrict__ biasF, float* __restrict__ maskF)
{
    const int i = blockIdx.x * 256 + threadIdx.x;
    const int NBF = 8 * 4096;        // 32768
    const int NMF = 64 * 4096;       // 262144
    const float L2E = 1.4426950408889634f;
    if (i < NBF) {
        const int h = i >> 12, rem = i & 4095;
        const int gi = rem >> 8, lane = (rem >> 2) & 63, r = rem & 3;
        const int mt = gi >> 2, nt = gi & 3;
        const int t = mt * 16 + (lane >> 4) * 4 + r;
        const int s = nt * 16 + (lane & 15);
        biasF[i] = (t < LW && s < LW) ? table[idx[t * LW + s] * NH + h] * L2E
                                      : 0.f;
    } else if (i < NBF + NMF) {
        const int j = i - NBF;
        const int w2 = j >> 12, rem = j & 4095;
        const int gi = rem >> 8, lane = (rem >> 2) & 63, r = rem & 3;
        const int mt = gi >> 2, nt = gi & 3;
        const int t = mt * 16 + (lane >> 4) * 4 + r;
        const int s = nt * 16 + (lane & 15);
        maskF[j] = (t < LW && s < LW) ? mask[w2 * (LW * LW) + t * LW + s] * L2E
                                      : 0.f;
    }
}

// ---------------- main: 2 waves, loop over h --------------------------------
__global__ __launch_bounds__(128, 4) void wa_mfma_kernel(
    const float* __restrict__ q, const float* __restrict__ k,
    const float* __restrict__ biasF, const float* __restrict__ maskF,
    float* __restrict__ score_out, float* __restrict__ attn_out)
{
    // Shared buffer, 12544 B, two overlapping uses (barrier-protected):
    //  K stage:  kHi = sB[0..2047]  (tile nt at nt*512 + lane*8, 8 u16/lane)
    //            kLo = sB[2048..4095]
    //  P planes: pHi = sB[0..3135]  (t*64 + swizzled s)
    //            pLo = sB[3136..6271]
    __shared__ __align__(16) unsigned short sB[6272];

    const int wv   = __builtin_amdgcn_readfirstlane((int)(threadIdx.x >> 6));
    const int b    = blockIdx.x;                   // one b per block
    const int w    = b & 63;
    const int lane = threadIdx.x & 63;
    const int l15  = lane & 15;
    const int g4   = lane >> 4;

    // scale * log2(e)
    const float scale2 = 0.17677669529663687f * 1.4426950408889634f;
    const float* mF = maskF + (size_t)w * 4096 + lane * 4;   // L1-hot in loop

    #pragma unroll 1
    for (int h = 0; h < NH; h++) {
        const int bh = b * NH + h;
        const float* qp = q + (size_t)bh * (32 * LW);
        const float* kp = k + (size_t)bh * (32 * LW);

        // ==== prologue: issue ALL raw loads back-to-back ====
        float k1raw[2][8], qraw[2][8], k2raw[2][8];
        #pragma unroll
        for (int ki = 0; ki < 2; ki++) {               // my half of K cols
            const int s  = (wv * 2 + ki) * 16 + l15;
            const int sc = s < LW ? s : (LW - 1);
            #pragma unroll
            for (int j = 0; j < 8; j++)
                k1raw[ki][j] = kp[(g4 * 8 + j) * LW + sc];
        }
        #pragma unroll
        for (int mi = 0; mi < 2; mi++) {               // my 2 Q row-tiles
            const int t  = (wv * 2 + mi) * 16 + l15;
            const int tc = t < LW ? t : (LW - 1);
            #pragma unroll
            for (int j = 0; j < 8; j++)
                qraw[mi][j] = qp[(g4 * 8 + j) * LW + tc];
        }
        {                                              // my K2 c-tile
            const int c = wv * 16 + l15;               // c < 32 always
            #pragma unroll
            for (int ks = 0; ks < 2; ks++)
                #pragma unroll
                for (int j = 0; j < 8; j++) {
                    const int s  = ks * 32 + g4 * 8 + j;
                    const int sc = s < LW ? s : (LW - 1);
                    k2raw[ks][j] = kp[c * LW + sc];
                }
        }

        // ==== split my K1 half -> LDS frag planes (b128 writes) ====
        #pragma unroll
        for (int ki = 0; ki < 2; ki++) {
            const int nt = wv * 2 + ki;
            Frag Kh, Kl;
            split8(k1raw[ki], Kh, Kl);
            *(s16x8*)&sB[nt * 512 + lane * 8]        = Kh.v;
            *(s16x8*)&sB[2048 + nt * 512 + lane * 8] = Kl.v;
        }

        // ==== split Q -> frags ====
        Frag Qh[2], Ql[2];
        split8(qraw[0], Qh[0], Ql[0]);
        split8(qraw[1], Qh[1], Ql[1]);

        lds_barrier();   // #1: K frags staged (K2 loads stay in flight)

        // ==== phase 1: S rows of this wave (3-pass split bf16) ====
        f32x4 acc[2][4];
        #pragma unroll
        for (int mi = 0; mi < 2; mi++)
            #pragma unroll
            for (int nt = 0; nt < 4; nt++)
                #pragma unroll
                for (int r = 0; r < 4; r++) acc[mi][nt][r] = 0.f;

        #pragma unroll
        for (int nt = 0; nt < 4; nt++) {
            Frag Kh, Kl;
            Kh.v = *(const s16x8*)&sB[nt * 512 + lane * 8];
            Kl.v = *(const s16x8*)&sB[2048 + nt * 512 + lane * 8];
            #pragma unroll
            for (int mi = 0; mi < 2; mi++) {
                acc[mi][nt] = MFMA16(Qh[mi].v, Kh.v, acc[mi][nt]);
                acc[mi][nt] = MFMA16(Ql[mi].v, Kh.v, acc[mi][nt]);
                acc[mi][nt] = MFMA16(Qh[mi].v, Kl.v, acc[mi][nt]);
            }
        }

        // ==== scale2 + bias + mask (log2e-folded); pad cols -> -1e30 ====
        const float* bF = biasF + (size_t)h * 4096 + lane * 4;
        #pragma unroll
        for (int mi = 0; mi < 2; mi++) {
            #pragma unroll
            for (int nt = 0; nt < 4; nt++) {
                const int gi = (wv * 2 + mi) * 4 + nt;
                const f32x4 bq = *(const f32x4*)(bF + gi * 256);
                const f32x4 mq = *(const f32x4*)(mF + gi * 256);
                const bool pad = (nt * 16 + l15) >= LW;
                #pragma unroll
                for (int r = 0; r < 4; r++) {
                    const float v2 = fmaf(acc[mi][nt][r], scale2,
                                          bq[r] + mq[r]);
                    acc[mi][nt][r] = pad ? -1e30f : v2;
                }
            }
        }

        // ==== softmax over s, no max-pass, native exp2 ====
        #pragma unroll
        for (int mi = 0; mi < 2; mi++) {
            #pragma unroll
            for (int r = 0; r < 4; r++) {
                float sm = 0.f;
                #pragma unroll
                for (int nt = 0; nt < 4; nt++) {
                    const float p = __builtin_exp2f(acc[mi][nt][r]);
                    acc[mi][nt][r] = p;
                    sm += p;
                }
                sm += __shfl_xor(sm, 1);
                sm += __shfl_xor(sm, 2);
                sm += __shfl_xor(sm, 4);
                sm += __shfl_xor(sm, 8);
                const float inv = 1.0f / sm;
                #pragma unroll
                for (int nt = 0; nt < 4; nt++) acc[mi][nt][r] *= inv;
            }
        }

        lds_barrier();   // #2: all K-LDS reads done; safe to overwrite with P

        // ==== pack this wave's P rows into hi/lo planes (swizzled) ====
        #pragma unroll
        for (int mi = 0; mi < 2; mi++) {
            #pragma unroll
            for (int r = 0; r < 4; r++) {
                const int t = (wv * 2 + mi) * 16 + g4 * 4 + r;
                if (t < LW) {
                    #pragma unroll
                    for (int nt = 0; nt < 4; nt++) {
                        const int s = nt * 16 + l15;
                        const float p = acc[mi][nt][r];
                        const unsigned short ph = f2bf(p);
                        const unsigned short pl = f2bf(p - bf2f(ph));
                        const unsigned idx = (unsigned)t * 64u
                            + ((((unsigned)s >> 3) ^ ((unsigned)t & 7u)) << 3)
                            + ((unsigned)s & 7u);
                        sB[idx]        = ph;
                        sB[3136 + idx] = pl;
                    }
                }
            }
        }

        lds_barrier();   // #3: P staged (both waves); stores free to fly

        // ==== attn writeout (stores overlap phase-3 compute) ====
        float* attn_base = attn_out + (size_t)bh * (LW * LW);
        #pragma unroll
        for (int mi = 0; mi < 2; mi++) {
            #pragma unroll
            for (int r = 0; r < 4; r++) {
                const int t = (wv * 2 + mi) * 16 + g4 * 4 + r;
                if (t < LW) {
                    #pragma unroll
                    for (int nt = 0; nt < 4; nt++) {
                        const int s = nt * 16 + l15;
                        if (s < LW) attn_base[t * LW + s] = acc[mi][nt][r];
                    }
                }
            }
        }

        // ==== split K2 into frags (loads have had 2 phases to land) ====
        Frag K2h[2], K2l[2];
        split8(k2raw[0], K2h[0], K2l[0]);
        split8(k2raw[1], K2h[1], K2l[1]);

        // ==== phase 3: score(c,t) = sum_s K(c,s) P(t,s) ====
        f32x4 acc2[4];
        #pragma unroll
        for (int nt = 0; nt < 4; nt++)
            #pragma unroll
            for (int r = 0; r < 4; r++) acc2[nt][r] = 0.f;

        #pragma unroll
        for (int ntt = 0; ntt < 4; ntt++) {
            const int t  = ntt * 16 + l15;
            const int tr = t < LW ? t : (LW - 1);      // clamped dead cols
            #pragma unroll
            for (int ks = 0; ks < 2; ks++) {
                const unsigned base = (unsigned)tr * 64u
                    + (((unsigned)(ks * 4 + g4) ^ ((unsigned)tr & 7u)) << 3);
                Frag Ph, Pl;
                Ph.v = *(const s16x8*)&sB[base];        // ds_read_b128
                Pl.v = *(const s16x8*)&sB[3136 + base]; // ds_read_b128
                acc2[ntt] = MFMA16(K2h[ks].v, Ph.v, acc2[ntt]);
                acc2[ntt] = MFMA16(K2l[ks].v, Ph.v, acc2[ntt]);
                acc2[ntt] = MFMA16(K2h[ks].v, Pl.v, acc2[ntt]);
            }
        }

        // ==== score writeout: direct from registers ====
        float* scp = score_out + (size_t)bh * (32 * LW);
        #pragma unroll
        for (int ntt = 0; ntt < 4; ntt++) {
            const int t = ntt * 16 + l15;
            if (t < LW) {
                #pragma unroll
                for (int r = 0; r < 4; r++) {
                    const int c = wv * 16 + g4 * 4 + r;
                    scp[c * LW + t] = acc2[ntt][r];
                }
            }
        }

        lds_barrier();   // #4: phase-3 P reads done before next K-stage write
    }
}

// ---------------- fallback (ws too small): VALU kernel ----------------------
__global__ __launch_bounds__(256, 4) void wa_fallback_kernel(
    const float* __restrict__ q, const float* __restrict__ k,
    const float* __restrict__ mask0, const float* __restrict__ table,
    const int* __restrict__ idx,
    float* __restrict__ score_out, float* __restrict__ attn_out)
{
    __shared__ float sPf[LW * LW];
    const int lane = threadIdx.x & 63;
    const int wv   = __builtin_amdgcn_readfirstlane((int)(threadIdx.x >> 6));
    const int bh   = blockIdx.x * 4 + wv;
    const int h    = bh & 7;
    const int w    = (bh >> 3) & 63;
    const int t    = lane;
    const int tc   = (t < LW) ? t : (LW - 1);

    const float* qp = q + (size_t)bh * (32 * LW);
    const float* kp = k + (size_t)bh * (32 * LW);

    float qreg[32];
    #pragma unroll
    for (int c = 0; c < 32; c++) qreg[c] = qp[c * LW + tc];

    float S[LW];
    #pragma unroll
    for (int s = 0; s < LW; s++) S[s] = 0.f;
    #pragma unroll
    for (int c = 0; c < 32; c++) {
        #pragma unroll
        for (int s = 0; s < LW; s++)
            S[s] = fmaf(qreg[c], kp[c * LW + s], S[s]);
    }

    const float scale = 0.17677669529663687f;
    const float* mrow = mask0 + (size_t)w * (LW * LW) + tc * LW;
    const int*   irow = idx + tc * LW;
    #pragma unroll
    for (int s = 0; s < LW; s++) {
        const float bm = table[irow[s] * NH + h] + mrow[s];
        S[s] = fmaf(S[s], scale, bm);
    }

    float m = S[0];
    #pragma unroll
    for (int s = 1; s < LW; s++) m = fmaxf(m, S[s]);
    float sum = 0.f;
    #pragma unroll
    for (int s = 0; s < LW; s++) { S[s] = __expf(S[s] - m); sum += S[s]; }
    const float invs = 1.0f / sum;
    #pragma unroll
    for (int s = 0; s < LW; s++) S[s] *= invs;

    float* attn_base = attn_out + (size_t)bh * (LW * LW);
    for (int turn = 0; turn < 4; turn++) {
        __syncthreads();
        if (turn == wv) {
            if (t < LW) {
                #pragma unroll
                for (int s = 0; s < LW; s++) sPf[t * LW + s] = S[s];
            }
            #pragma unroll
            for (int it = 0; it < 38; it++) {
                const int i = it * 64 + lane;
                if (i < LW * LW) attn_base[i] = sPf[i];
            }
        }
    }

    float* sc = score_out + (size_t)bh * (32 * LW);
    #pragma unroll
    for (int c = 0; c < 32; c++) {
        float a = 0.f;
        #pragma unroll
        for (int s = 0; s < LW; s++) a = fmaf(S[s], kp[c * LW + s], a);
        if (t < LW) sc[c * LW + t] = a;
    }
}

extern "C" void kernel_launch(void* const* d_in, const int* in_sizes, int n_in,
                              void* d_out, int out_size, void* d_ws, size_t ws_size,
                              hipStream_t stream) {
    const float* q     = (const float*)d_in[0];
    const float* k     = (const float*)d_in[1];
    // d_in[2] = v, unused: reference reassigns v = k
    const float* mask  = (const float*)d_in[3];
    const float* table = (const float*)d_in[4];
    const int*   idx   = (const int*)d_in[5];

    float* score_out = (float*)d_out;
    float* attn_out  = score_out + (size_t)2048 * 256 * 49;

    const size_t NBF = (size_t)8 * 4096;     // 32768 floats
    const size_t NMF = (size_t)64 * 4096;    // 262144 floats

    if (ws_size >= (NBF + NMF) * sizeof(float)) {
        float* biasF = (float*)d_ws;
        float* maskF = biasF + NBF;
        const int tot = (int)(NBF + NMF);
        prep_frag_kernel<<<(tot + 255) / 256, 256, 0, stream>>>(
            mask, table, idx, biasF, maskF);
        wa_mfma_kernel<<<2048, 128, 0, stream>>>(
            q, k, biasF, maskF, score_out, attn_out);
    } else {
        wa_fallback_kernel<<<4096, 256, 0, stream>>>(
            q, k, mask, table, idx, score_out, attn_out);
    }
}

// Round 10
// 497.297 us; speedup vs baseline: 1.3473x; 1.3473x over previous
//
#include <hip/hip_runtime.h>
#include <hip/hip_bf16.h>
#include <math.h>

// WindowAttention: B=2048, C=256, H=8, d_k=32, wh=ww=7 -> L=49, nW=64.
// Reference reassigns v = k. Outputs: score (2048*256*49) then attn
// (2048*8*49*49), fp32, concatenated in d_out.
//
// MFMA design, R10: R8 body exactly (2 waves per (b,h), 16384 blocks x 128
// threads, K1-sharing via LDS, P hi/lo planes, lgkm-only barriers, no-max
// softmax, HW bf16 cvt) + BF16 bias/mask tables.
//
// R5-R9 model (counter-derived): dur pinned ~178us across 31-52% occupancy
// with all pipes <30% busy -> throughput cap on outstanding memory requests
// (L1 miss tracking), not latency/BW. Read segments are the currency; the
// fp32 frag-ordered bias/mask tables were 512MB of ~770MB total reads.
// bf16 tables halve that (values: bias ~0.03 -> err 1e-4; mask -144.27 ->
// bf16 -144, exp2 of both ~1e-43 ~= 0). exp2-fold (tables premultiplied by
// log2e, scale2 = scale*log2e) validated in R9 (absmax 0.0078).
//
// R9 lesson: NO h-loop (loop-carried state + "memory"-clobber barriers ->
// scratch spill, FETCH/WRITE inflation). Straight-line body only.
// Spill tripwire (R2-R4): WRITE_SIZE >> 256MB.

#define LW 49
#define NH 8

typedef short s16x8 __attribute__((ext_vector_type(8)));
typedef float f32x4 __attribute__((ext_vector_type(4)));
typedef unsigned short u16x4 __attribute__((ext_vector_type(4)));

union Frag { s16x8 v; unsigned short u[8]; };

__device__ __forceinline__ unsigned short f2bf(float x) {
    return __builtin_bit_cast(unsigned short, __float2bfloat16(x));
}
__device__ __forceinline__ float bf2f(unsigned short h) {
    return __uint_as_float(((unsigned)h) << 16);
}
// hi = bf16(x); lo = bf16(x - hi). 3-pass MFMA (Ah*Bh + Al*Bh + Ah*Bl)
// gives ~fp32 accuracy.
__device__ __forceinline__ void split8(const float* xf, Frag& hi, Frag& lo) {
    #pragma unroll
    for (int j = 0; j < 8; j++) {
        const unsigned short hb = f2bf(xf[j]);
        hi.u[j] = hb;
        lo.u[j] = f2bf(xf[j] - bf2f(hb));
    }
}

// LDS-only barrier: does NOT drain vmcnt (global loads/stores keep flying).
__device__ __forceinline__ void lds_barrier() {
    asm volatile("s_waitcnt lgkmcnt(0)" ::: "memory");
    __builtin_amdgcn_s_barrier();
    asm volatile("" ::: "memory");
    __builtin_amdgcn_sched_barrier(0);
}

#define MFMA16(A, B, C) __builtin_amdgcn_mfma_f32_16x16x32_bf16((A), (B), (C), 0, 0, 0)

// ---------------- prep: bias & mask -> bf16, frag order, log2e-folded -------
// biasB[h][gi][lane][r], maskB[w][gi][lane][r] as bf16 (ushort); value at
// (t = mt*16+(lane>>4)*4+r, s = nt*16+(lane&15)) * log2(e); 0 at pads.
__global__ __launch_bounds__(256) void prep_frag_kernel(
    const float* __restrict__ mask, const float* __restrict__ table,
    const int* __restrict__ idx,
    unsigned short* __restrict__ biasB, unsigned short* __restrict__ maskB)
{
    const int i = blockIdx.x * 256 + threadIdx.x;
    const int NBF = 8 * 4096;        // 32768
    const int NMF = 64 * 4096;       // 262144
    const float L2E = 1.4426950408889634f;
    if (i < NBF) {
        const int h = i >> 12, rem = i & 4095;
        const int gi = rem >> 8, lane = (rem >> 2) & 63, r = rem & 3;
        const int mt = gi >> 2, nt = gi & 3;
        const int t = mt * 16 + (lane >> 4) * 4 + r;
        const int s = nt * 16 + (lane & 15);
        const float v = (t < LW && s < LW)
                      ? table[idx[t * LW + s] * NH + h] * L2E : 0.f;
        biasB[i] = f2bf(v);
    } else if (i < NBF + NMF) {
        const int j = i - NBF;
        const int w2 = j >> 12, rem = j & 4095;
        const int gi = rem >> 8, lane = (rem >> 2) & 63, r = rem & 3;
        const int mt = gi >> 2, nt = gi & 3;
        const int t = mt * 16 + (lane >> 4) * 4 + r;
        const int s = nt * 16 + (lane & 15);
        const float v = (t < LW && s < LW)
                      ? mask[w2 * (LW * LW) + t * LW + s] * L2E : 0.f;
        maskB[j] = f2bf(v);
    }
}

// ---------------- main: 2 waves per (b,h) -----------------------------------
__global__ __launch_bounds__(128, 4) void wa_mfma_kernel(
    const float* __restrict__ q, const float* __restrict__ k,
    const unsigned short* __restrict__ biasB,
    const unsigned short* __restrict__ maskB,
    float* __restrict__ score_out, float* __restrict__ attn_out)
{
    // Shared buffer, 12544 B, two overlapping uses (barrier-protected):
    //  K stage:  kHi = sB[0..2047]  (tile nt at nt*512 + lane*8, 8 u16/lane)
    //            kLo = sB[2048..4095]
    //  P planes: pHi = sB[0..3135]  (t*64 + swizzled s)
    //            pLo = sB[3136..6271]
    __shared__ __align__(16) unsigned short sB[6272];

    const int wv   = __builtin_amdgcn_readfirstlane((int)(threadIdx.x >> 6));
    const int bh   = blockIdx.x;
    const int h    = bh & 7;
    const int w    = (bh >> 3) & 63;
    const int lane = threadIdx.x & 63;
    const int l15  = lane & 15;
    const int g4   = lane >> 4;

    const float* qp = q + (size_t)bh * (32 * LW);
    const float* kp = k + (size_t)bh * (32 * LW);

    // ==== prologue: issue ALL raw loads back-to-back ====
    float k1raw[2][8], qraw[2][8], k2raw[2][8];
    #pragma unroll
    for (int ki = 0; ki < 2; ki++) {               // my half of K cols
        const int s  = (wv * 2 + ki) * 16 + l15;
        const int sc = s < LW ? s : (LW - 1);
        #pragma unroll
        for (int j = 0; j < 8; j++) k1raw[ki][j] = kp[(g4 * 8 + j) * LW + sc];
    }
    #pragma unroll
    for (int mi = 0; mi < 2; mi++) {               // my 2 Q row-tiles
        const int t  = (wv * 2 + mi) * 16 + l15;
        const int tc = t < LW ? t : (LW - 1);
        #pragma unroll
        for (int j = 0; j < 8; j++) qraw[mi][j] = qp[(g4 * 8 + j) * LW + tc];
    }
    {                                              // my K2 c-tile (phase 3)
        const int c = wv * 16 + l15;               // c < 32 always
        #pragma unroll
        for (int ks = 0; ks < 2; ks++)
            #pragma unroll
            for (int j = 0; j < 8; j++) {
                const int s  = ks * 32 + g4 * 8 + j;
                const int sc = s < LW ? s : (LW - 1);   // P at pad s is 0
                k2raw[ks][j] = kp[c * LW + sc];
            }
    }

    // ==== bias/mask bf16 loads (8B/lane, 512B/instr) — issued early so
    //      the ~L2 latency hides under K1 split + barrier + phase 1 ====
    u16x4 bq4[2][4], mq4[2][4];
    {
        const unsigned short* bF = biasB + (size_t)h * 4096 + lane * 4;
        const unsigned short* mF = maskB + (size_t)w * 4096 + lane * 4;
        #pragma unroll
        for (int mi = 0; mi < 2; mi++)
            #pragma unroll
            for (int nt = 0; nt < 4; nt++) {
                const int gi = (wv * 2 + mi) * 4 + nt;
                bq4[mi][nt] = *(const u16x4*)(bF + gi * 256);
                mq4[mi][nt] = *(const u16x4*)(mF + gi * 256);
            }
    }

    // ==== split my K1 half -> LDS frag planes (b128 writes) ====
    #pragma unroll
    for (int ki = 0; ki < 2; ki++) {
        const int nt = wv * 2 + ki;
        Frag Kh, Kl;
        split8(k1raw[ki], Kh, Kl);
        *(s16x8*)&sB[nt * 512 + lane * 8]        = Kh.v;
        *(s16x8*)&sB[2048 + nt * 512 + lane * 8] = Kl.v;
    }

    // ==== split Q -> frags ====
    Frag Qh[2], Ql[2];
    split8(qraw[0], Qh[0], Ql[0]);
    split8(qraw[1], Qh[1], Ql[1]);

    lds_barrier();   // #1: K frags staged (K2/bias/mask loads stay in flight)

    // ==== phase 1: S rows of this wave (3-pass split bf16) ====
    f32x4 acc[2][4];
    #pragma unroll
    for (int mi = 0; mi < 2; mi++)
        #pragma unroll
        for (int nt = 0; nt < 4; nt++)
            #pragma unroll
            for (int r = 0; r < 4; r++) acc[mi][nt][r] = 0.f;

    #pragma unroll
    for (int nt = 0; nt < 4; nt++) {
        Frag Kh, Kl;
        Kh.v = *(const s16x8*)&sB[nt * 512 + lane * 8];
        Kl.v = *(const s16x8*)&sB[2048 + nt * 512 + lane * 8];
        #pragma unroll
        for (int mi = 0; mi < 2; mi++) {
            acc[mi][nt] = MFMA16(Qh[mi].v, Kh.v, acc[mi][nt]);
            acc[mi][nt] = MFMA16(Ql[mi].v, Kh.v, acc[mi][nt]);
            acc[mi][nt] = MFMA16(Qh[mi].v, Kl.v, acc[mi][nt]);
        }
    }

    // ==== scale2 + bias + mask (bf16 unpack); pad cols -> -1e30 ====
    const float scale2 = 0.17677669529663687f * 1.4426950408889634f;
    #pragma unroll
    for (int mi = 0; mi < 2; mi++) {
        #pragma unroll
        for (int nt = 0; nt < 4; nt++) {
            const bool pad = (nt * 16 + l15) >= LW;
            #pragma unroll
            for (int r = 0; r < 4; r++) {
                const float bm = bf2f(bq4[mi][nt][r]) + bf2f(mq4[mi][nt][r]);
                const float v2 = fmaf(acc[mi][nt][r], scale2, bm);
                acc[mi][nt][r] = pad ? -1e30f : v2;
            }
        }
    }

    // ==== softmax over s, no max-pass, native exp2 (exact transform) ====
    #pragma unroll
    for (int mi = 0; mi < 2; mi++) {
        #pragma unroll
        for (int r = 0; r < 4; r++) {
            float sm = 0.f;
            #pragma unroll
            for (int nt = 0; nt < 4; nt++) {
                const float p = __builtin_exp2f(acc[mi][nt][r]);
                acc[mi][nt][r] = p;
                sm += p;
            }
            sm += __shfl_xor(sm, 1);
            sm += __shfl_xor(sm, 2);
            sm += __shfl_xor(sm, 4);
            sm += __shfl_xor(sm, 8);
            const float inv = 1.0f / sm;
            #pragma unroll
            for (int nt = 0; nt < 4; nt++) acc[mi][nt][r] *= inv;
        }
    }

    lds_barrier();   // #2: all K-LDS reads done; safe to overwrite with P

    // ==== pack this wave's P rows into hi/lo planes (swizzled) ====
    #pragma unroll
    for (int mi = 0; mi < 2; mi++) {
        #pragma unroll
        for (int r = 0; r < 4; r++) {
            const int t = (wv * 2 + mi) * 16 + g4 * 4 + r;
            if (t < LW) {
                #pragma unroll
                for (int nt = 0; nt < 4; nt++) {
                    const int s = nt * 16 + l15;
                    const float p = acc[mi][nt][r];
                    const unsigned short ph = f2bf(p);
                    const unsigned short pl = f2bf(p - bf2f(ph));
                    const unsigned idx = (unsigned)t * 64u
                        + ((((unsigned)s >> 3) ^ ((unsigned)t & 7u)) << 3)
                        + ((unsigned)s & 7u);
                    sB[idx]        = ph;
                    sB[3136 + idx] = pl;
                }
            }
        }
    }

    lds_barrier();   // #3: P staged (both waves); stores free to fly

    // ==== attn writeout (stores overlap phase-3 compute) ====
    float* attn_base = attn_out + (size_t)bh * (LW * LW);
    #pragma unroll
    for (int mi = 0; mi < 2; mi++) {
        #pragma unroll
        for (int r = 0; r < 4; r++) {
            const int t = (wv * 2 + mi) * 16 + g4 * 4 + r;
            if (t < LW) {
                #pragma unroll
                for (int nt = 0; nt < 4; nt++) {
                    const int s = nt * 16 + l15;
                    if (s < LW) attn_base[t * LW + s] = acc[mi][nt][r];
                }
            }
        }
    }

    // ==== split K2 into frags (loads have had 2 full phases to land) ====
    Frag K2h[2], K2l[2];
    split8(k2raw[0], K2h[0], K2l[0]);
    split8(k2raw[1], K2h[1], K2l[1]);

    // ==== phase 3: score(c,t) = sum_s K(c,s) P(t,s); A-frags via b128 ====
    f32x4 acc2[4];
    #pragma unroll
    for (int nt = 0; nt < 4; nt++)
        #pragma unroll
        for (int r = 0; r < 4; r++) acc2[nt][r] = 0.f;

    #pragma unroll
    for (int ntt = 0; ntt < 4; ntt++) {
        const int t  = ntt * 16 + l15;
        const int tr = t < LW ? t : (LW - 1);          // clamped dead cols
        #pragma unroll
        for (int ks = 0; ks < 2; ks++) {
            const unsigned base = (unsigned)tr * 64u
                + (((unsigned)(ks * 4 + g4) ^ ((unsigned)tr & 7u)) << 3);
            Frag Ph, Pl;
            Ph.v = *(const s16x8*)&sB[base];            // ds_read_b128
            Pl.v = *(const s16x8*)&sB[3136 + base];     // ds_read_b128
            acc2[ntt] = MFMA16(K2h[ks].v, Ph.v, acc2[ntt]);
            acc2[ntt] = MFMA16(K2l[ks].v, Ph.v, acc2[ntt]);
            acc2[ntt] = MFMA16(K2h[ks].v, Pl.v, acc2[ntt]);
        }
    }

    // ==== score writeout: direct from registers ====
    float* scp = score_out + (size_t)bh * (32 * LW);
    #pragma unroll
    for (int ntt = 0; ntt < 4; ntt++) {
        const int t = ntt * 16 + l15;
        if (t < LW) {
            #pragma unroll
            for (int r = 0; r < 4; r++) {
                const int c = wv * 16 + g4 * 4 + r;
                scp[c * LW + t] = acc2[ntt][r];
            }
        }
    }
}

// ---------------- fallback (ws too small): VALU kernel ----------------------
__global__ __launch_bounds__(256, 4) void wa_fallback_kernel(
    const float* __restrict__ q, const float* __restrict__ k,
    const float* __restrict__ mask0, const float* __restrict__ table,
    const int* __restrict__ idx,
    float* __restrict__ score_out, float* __restrict__ attn_out)
{
    __shared__ float sPf[LW * LW];
    const int lane = threadIdx.x & 63;
    const int wv   = __builtin_amdgcn_readfirstlane((int)(threadIdx.x >> 6));
    const int bh   = blockIdx.x * 4 + wv;
    const int h    = bh & 7;
    const int w    = (bh >> 3) & 63;
    const int t    = lane;
    const int tc   = (t < LW) ? t : (LW - 1);

    const float* qp = q + (size_t)bh * (32 * LW);
    const float* kp = k + (size_t)bh * (32 * LW);

    float qreg[32];
    #pragma unroll
    for (int c = 0; c < 32; c++) qreg[c] = qp[c * LW + tc];

    float S[LW];
    #pragma unroll
    for (int s = 0; s < LW; s++) S[s] = 0.f;
    #pragma unroll
    for (int c = 0; c < 32; c++) {
        #pragma unroll
        for (int s = 0; s < LW; s++)
            S[s] = fmaf(qreg[c], kp[c * LW + s], S[s]);
    }

    const float scale = 0.17677669529663687f;
    const float* mrow = mask0 + (size_t)w * (LW * LW) + tc * LW;
    const int*   irow = idx + tc * LW;
    #pragma unroll
    for (int s = 0; s < LW; s++) {
        const float bm = table[irow[s] * NH + h] + mrow[s];
        S[s] = fmaf(S[s], scale, bm);
    }

    float m = S[0];
    #pragma unroll
    for (int s = 1; s < LW; s++) m = fmaxf(m, S[s]);
    float sum = 0.f;
    #pragma unroll
    for (int s = 0; s < LW; s++) { S[s] = __expf(S[s] - m); sum += S[s]; }
    const float invs = 1.0f / sum;
    #pragma unroll
    for (int s = 0; s < LW; s++) S[s] *= invs;

    float* attn_base = attn_out + (size_t)bh * (LW * LW);
    for (int turn = 0; turn < 4; turn++) {
        __syncthreads();
        if (turn == wv) {
            if (t < LW) {
                #pragma unroll
                for (int s = 0; s < LW; s++) sPf[t * LW + s] = S[s];
            }
            #pragma unroll
            for (int it = 0; it < 38; it++) {
                const int i = it * 64 + lane;
                if (i < LW * LW) attn_base[i] = sPf[i];
            }
        }
    }

    float* sc = score_out + (size_t)bh * (32 * LW);
    #pragma unroll
    for (int c = 0; c < 32; c++) {
        float a = 0.f;
        #pragma unroll
        for (int s = 0; s < LW; s++) a = fmaf(S[s], kp[c * LW + s], a);
        if (t < LW) sc[c * LW + t] = a;
    }
}

extern "C" void kernel_launch(void* const* d_in, const int* in_sizes, int n_in,
                              void* d_out, int out_size, void* d_ws, size_t ws_size,
                              hipStream_t stream) {
    const float* q     = (const float*)d_in[0];
    const float* k     = (const float*)d_in[1];
    // d_in[2] = v, unused: reference reassigns v = k
    const float* mask  = (const float*)d_in[3];
    const float* table = (const float*)d_in[4];
    const int*   idx   = (const int*)d_in[5];

    float* score_out = (float*)d_out;
    float* attn_out  = score_out + (size_t)2048 * 256 * 49;

    const size_t NBF = (size_t)8 * 4096;     // 32768 bf16 elems
    const size_t NMF = (size_t)64 * 4096;    // 262144 bf16 elems

    if (ws_size >= (NBF + NMF) * sizeof(unsigned short)) {
        unsigned short* biasB = (unsigned short*)d_ws;
        unsigned short* maskB = biasB + NBF;
        const int tot = (int)(NBF + NMF);
        prep_frag_kernel<<<(tot + 255) / 256, 256, 0, stream>>>(
            mask, table, idx, biasB, maskB);
        wa_mfma_kernel<<<16384, 128, 0, stream>>>(
            q, k, biasB, maskB, score_out, attn_out);
    } else {
        wa_fallback_kernel<<<4096, 256, 0, stream>>>(
            q, k, mask, table, idx, score_out, attn_out);
    }
}

// Round 11
// 461.095 us; speedup vs baseline: 1.4530x; 1.0785x over previous
//
#include <hip/hip_runtime.h>
#include <hip/hip_bf16.h>
#include <math.h>

// WindowAttention: B=2048, C=256, H=8, d_k=32, wh=ww=7 -> L=49, nW=64.
// Reference reassigns v = k. Outputs: score (2048*256*49) then attn
// (2048*8*49*49), fp32, concatenated in d_out.
//
// MFMA design, R11: test of the GLOBAL-REQUEST-PORT theory (R5-R10: dur
// pinned 171-200us across occupancy 31-52%, VALU 28-48%, traffic knobs
// +-2x -- the only never-varied quantity is ~112 global memory
// instructions/wave hammering the per-CU L1/TA port).
//
// Load side this round:
//  - K+Q staged RAW to LDS via 7x global_load_lds dwordx4 per wave
//    (wave0->K, wave1->Q; linear dst per m104 rule). Replaces 48 scalar
//    strided global loads; frag gathers become ds_read_b32.
//  - K2 (phase 3) gathered from the SAME raw K in LDS right after phase 1
//    -> K read once per bh (kills 16 more global loads, halves K L2 reads).
//  - stage barrier = vmcnt(0)+lgkm raw barrier BEFORE table loads issue,
//    so the 16 bf16 table loads still fly across phase 1.
// Stores unchanged (mechanism isolation; 48 direct stores proven clean).
//
// LDS (12.8KB/block): raw K [0,6400) + raw Q [6400,12800); P hi/lo planes
// reuse [0,12544) after phase 1 (lgkm barriers). Tail staging instr is
// lane<16-masked with gptr clamp (no OOB read at bh=16383; LDS pad bytes
// [6272,6400) never read: max raw index = 31*49+48 -> byte 6268).
//
// Carried: bf16 frag-order tables (R10), exp2-fold + no-max softmax
// (R9/R10, refcheck'd absmax 0.0078), lgkm-only barriers (R8), hw bf16
// cvt (R8), direct register stores (R5 spill lesson: WRITE>>256MB = spill
// tripwire).

#define LW 49
#define NH 8

typedef short s16x8 __attribute__((ext_vector_type(8)));
typedef float f32x4 __attribute__((ext_vector_type(4)));
typedef unsigned short u16x4 __attribute__((ext_vector_type(4)));

union Frag { s16x8 v; unsigned short u[8]; };

__device__ __forceinline__ unsigned short f2bf(float x) {
    return __builtin_bit_cast(unsigned short, __float2bfloat16(x));
}
__device__ __forceinline__ float bf2f(unsigned short h) {
    return __uint_as_float(((unsigned)h) << 16);
}
// hi = bf16(x); lo = bf16(x - hi). 3-pass MFMA (Ah*Bh + Al*Bh + Ah*Bl)
// gives ~fp32 accuracy.
__device__ __forceinline__ void split8(const float* xf, Frag& hi, Frag& lo) {
    #pragma unroll
    for (int j = 0; j < 8; j++) {
        const unsigned short hb = f2bf(xf[j]);
        hi.u[j] = hb;
        lo.u[j] = f2bf(xf[j] - bf2f(hb));
    }
}

// LDS-only barrier: does NOT drain vmcnt (global loads/stores keep flying).
__device__ __forceinline__ void lds_barrier() {
    asm volatile("s_waitcnt lgkmcnt(0)" ::: "memory");
    __builtin_amdgcn_s_barrier();
    asm volatile("" ::: "memory");
    __builtin_amdgcn_sched_barrier(0);
}
// Stage barrier: drains vmcnt too (global_load_lds lands via vmcnt).
// Placed BEFORE table loads are issued, so only staging is drained.
__device__ __forceinline__ void stage_barrier() {
    asm volatile("s_waitcnt vmcnt(0) lgkmcnt(0)" ::: "memory");
    __builtin_amdgcn_s_barrier();
    asm volatile("" ::: "memory");
    __builtin_amdgcn_sched_barrier(0);
}

__device__ __forceinline__ void load_lds16(const void* g, void* l) {
    __builtin_amdgcn_global_load_lds(
        (const __attribute__((address_space(1))) void*)g,
        (__attribute__((address_space(3))) void*)l, 16, 0, 0);
}

#define MFMA16(A, B, C) __builtin_amdgcn_mfma_f32_16x16x32_bf16((A), (B), (C), 0, 0, 0)

// ---------------- prep: bias & mask -> bf16, frag order, log2e-folded -------
__global__ __launch_bounds__(256) void prep_frag_kernel(
    const float* __restrict__ mask, const float* __restrict__ table,
    const int* __restrict__ idx,
    unsigned short* __restrict__ biasB, unsigned short* __restrict__ maskB)
{
    const int i = blockIdx.x * 256 + threadIdx.x;
    const int NBF = 8 * 4096;        // 32768
    const int NMF = 64 * 4096;       // 262144
    const float L2E = 1.4426950408889634f;
    if (i < NBF) {
        const int h = i >> 12, rem = i & 4095;
        const int gi = rem >> 8, lane = (rem >> 2) & 63, r = rem & 3;
        const int mt = gi >> 2, nt = gi & 3;
        const int t = mt * 16 + (lane >> 4) * 4 + r;
        const int s = nt * 16 + (lane & 15);
        const float v = (t < LW && s < LW)
                      ? table[idx[t * LW + s] * NH + h] * L2E : 0.f;
        biasB[i] = f2bf(v);
    } else if (i < NBF + NMF) {
        const int j = i - NBF;
        const int w2 = j >> 12, rem = j & 4095;
        const int gi = rem >> 8, lane = (rem >> 2) & 63, r = rem & 3;
        const int mt = gi >> 2, nt = gi & 3;
        const int t = mt * 16 + (lane >> 4) * 4 + r;
        const int s = nt * 16 + (lane & 15);
        const float v = (t < LW && s < LW)
                      ? mask[w2 * (LW * LW) + t * LW + s] * L2E : 0.f;
        maskB[j] = f2bf(v);
    }
}

// ---------------- main: 2 waves per (b,h) -----------------------------------
__global__ __launch_bounds__(128, 4) void wa_mfma_kernel(
    const float* __restrict__ q, const float* __restrict__ k,
    const unsigned short* __restrict__ biasB,
    const unsigned short* __restrict__ maskB,
    float* __restrict__ score_out, float* __restrict__ attn_out)
{
    // 12800 B shared buffer, two overlapping uses (barrier-protected):
    //  stage:   raw K fp32 [0,6400)  (row-major 32x49, 196B rows)
    //           raw Q fp32 [6400,12800)
    //  P planes (after phase 1): pHi u16 [0,6272), pLo u16 [6272,12544)
    __shared__ __align__(16) char sRaw[12800];

    const int wv   = __builtin_amdgcn_readfirstlane((int)(threadIdx.x >> 6));
    const int bh   = blockIdx.x;
    const int h    = bh & 7;
    const int w    = (bh >> 3) & 63;
    const int lane = threadIdx.x & 63;
    const int l15  = lane & 15;
    const int g4   = lane >> 4;

    const float* qp = q + (size_t)bh * (32 * LW);
    const float* kp = k + (size_t)bh * (32 * LW);

    char* ldsK = sRaw;
    char* ldsQ = sRaw + 6400;

    // ==== stage raw K (wave0) / raw Q (wave1) via global_load_lds ====
    {
        const char* src = (wv == 0) ? (const char*)kp : (const char*)qp;
        char*       dst = (wv == 0) ? ldsK : ldsQ;
        #pragma unroll
        for (int i = 0; i < 6; i++)
            load_lds16(src + i * 1024 + lane * 16, dst + i * 1024);
        if (lane < 16) {
            // tail [6144,6400): lanes 8..15 write pad, gptr clamped in-bounds
            const int off = (lane < 8) ? lane * 16 : 112;
            load_lds16(src + 6144 + off, dst + 6144);
        }
    }

    stage_barrier();   // staging landed (both waves); tables not yet issued

    // ==== bias/mask bf16 loads (8B/lane) — fly across phase 1 ====
    u16x4 bq4[2][4], mq4[2][4];
    {
        const unsigned short* bF = biasB + (size_t)h * 4096 + lane * 4;
        const unsigned short* mF = maskB + (size_t)w * 4096 + lane * 4;
        #pragma unroll
        for (int mi = 0; mi < 2; mi++)
            #pragma unroll
            for (int nt = 0; nt < 4; nt++) {
                const int gi = (wv * 2 + mi) * 4 + nt;
                bq4[mi][nt] = *(const u16x4*)(bF + gi * 256);
                mq4[mi][nt] = *(const u16x4*)(mF + gi * 256);
            }
    }

    const float* sKf = (const float*)ldsK;
    const float* sQf = (const float*)ldsQ;

    // ==== Q frags from LDS raw ====
    Frag Qh[2], Ql[2];
    #pragma unroll
    for (int mi = 0; mi < 2; mi++) {
        const int t  = (wv * 2 + mi) * 16 + l15;
        const int tc = t < LW ? t : (LW - 1);
        float xf[8];
        #pragma unroll
        for (int j = 0; j < 8; j++) xf[j] = sQf[(g4 * 8 + j) * LW + tc];
        split8(xf, Qh[mi], Ql[mi]);
    }

    // ==== phase 1: S rows of this wave (K frags gathered per nt) ====
    f32x4 acc[2][4];
    #pragma unroll
    for (int mi = 0; mi < 2; mi++)
        #pragma unroll
        for (int nt = 0; nt < 4; nt++)
            #pragma unroll
            for (int r = 0; r < 4; r++) acc[mi][nt][r] = 0.f;

    #pragma unroll
    for (int nt = 0; nt < 4; nt++) {
        const int s  = nt * 16 + l15;
        const int sc = s < LW ? s : (LW - 1);
        float xf[8];
        #pragma unroll
        for (int j = 0; j < 8; j++) xf[j] = sKf[(g4 * 8 + j) * LW + sc];
        Frag Kh, Kl;
        split8(xf, Kh, Kl);
        #pragma unroll
        for (int mi = 0; mi < 2; mi++) {
            acc[mi][nt] = MFMA16(Qh[mi].v, Kh.v, acc[mi][nt]);
            acc[mi][nt] = MFMA16(Ql[mi].v, Kh.v, acc[mi][nt]);
            acc[mi][nt] = MFMA16(Qh[mi].v, Kl.v, acc[mi][nt]);
        }
    }

    // ==== K2 frags from the SAME raw K (before P pack overwrites it) ====
    Frag K2h[2], K2l[2];
    {
        const int c = wv * 16 + l15;                   // c < 32 always
        #pragma unroll
        for (int ks = 0; ks < 2; ks++) {
            float xf[8];
            #pragma unroll
            for (int j = 0; j < 8; j++) {
                const int s  = ks * 32 + g4 * 8 + j;
                const int sc = s < LW ? s : (LW - 1);  // P at pad s is 0
                xf[j] = sKf[c * LW + sc];
            }
            split8(xf, K2h[ks], K2l[ks]);
        }
    }

    // ==== scale2 + bias + mask (bf16 unpack); pad cols -> -1e30 ====
    const float scale2 = 0.17677669529663687f * 1.4426950408889634f;
    #pragma unroll
    for (int mi = 0; mi < 2; mi++) {
        #pragma unroll
        for (int nt = 0; nt < 4; nt++) {
            const bool pad = (nt * 16 + l15) >= LW;
            #pragma unroll
            for (int r = 0; r < 4; r++) {
                const float bm = bf2f(bq4[mi][nt][r]) + bf2f(mq4[mi][nt][r]);
                const float v2 = fmaf(acc[mi][nt][r], scale2, bm);
                acc[mi][nt][r] = pad ? -1e30f : v2;
            }
        }
    }

    // ==== softmax over s, no max-pass, native exp2 (exact transform) ====
    #pragma unroll
    for (int mi = 0; mi < 2; mi++) {
        #pragma unroll
        for (int r = 0; r < 4; r++) {
            float sm = 0.f;
            #pragma unroll
            for (int nt = 0; nt < 4; nt++) {
                const float p = __builtin_exp2f(acc[mi][nt][r]);
                acc[mi][nt][r] = p;
                sm += p;
            }
            sm += __shfl_xor(sm, 1);
            sm += __shfl_xor(sm, 2);
            sm += __shfl_xor(sm, 4);
            sm += __shfl_xor(sm, 8);
            const float inv = 1.0f / sm;
            #pragma unroll
            for (int nt = 0; nt < 4; nt++) acc[mi][nt][r] *= inv;
        }
    }

    lds_barrier();   // #2: all raw-LDS reads done (both waves); reuse for P

    // ==== pack this wave's P rows into hi/lo planes (swizzled) ====
    unsigned short* sB = (unsigned short*)sRaw;
    #pragma unroll
    for (int mi = 0; mi < 2; mi++) {
        #pragma unroll
        for (int r = 0; r < 4; r++) {
            const int t = (wv * 2 + mi) * 16 + g4 * 4 + r;
            if (t < LW) {
                #pragma unroll
                for (int nt = 0; nt < 4; nt++) {
                    const int s = nt * 16 + l15;
                    const float p = acc[mi][nt][r];
                    const unsigned short ph = f2bf(p);
                    const unsigned short pl = f2bf(p - bf2f(ph));
                    const unsigned idx = (unsigned)t * 64u
                        + ((((unsigned)s >> 3) ^ ((unsigned)t & 7u)) << 3)
                        + ((unsigned)s & 7u);
                    sB[idx]        = ph;
                    sB[3136 + idx] = pl;
                }
            }
        }
    }

    lds_barrier();   // #3: P staged (both waves); stores free to fly

    // ==== attn writeout (direct register stores; overlap phase 3) ====
    float* attn_base = attn_out + (size_t)bh * (LW * LW);
    #pragma unroll
    for (int mi = 0; mi < 2; mi++) {
        #pragma unroll
        for (int r = 0; r < 4; r++) {
            const int t = (wv * 2 + mi) * 16 + g4 * 4 + r;
            if (t < LW) {
                #pragma unroll
                for (int nt = 0; nt < 4; nt++) {
                    const int s = nt * 16 + l15;
                    if (s < LW) attn_base[t * LW + s] = acc[mi][nt][r];
                }
            }
        }
    }

    // ==== phase 3: score(c,t) = sum_s K(c,s) P(t,s); A-frags via b128 ====
    f32x4 acc2[4];
    #pragma unroll
    for (int nt = 0; nt < 4; nt++)
        #pragma unroll
        for (int r = 0; r < 4; r++) acc2[nt][r] = 0.f;

    #pragma unroll
    for (int ntt = 0; ntt < 4; ntt++) {
        const int t  = ntt * 16 + l15;
        const int tr = t < LW ? t : (LW - 1);          // clamped dead cols
        #pragma unroll
        for (int ks = 0; ks < 2; ks++) {
            const unsigned base = (unsigned)tr * 64u
                + (((unsigned)(ks * 4 + g4) ^ ((unsigned)tr & 7u)) << 3);
            Frag Ph, Pl;
            Ph.v = *(const s16x8*)&sB[base];            // ds_read_b128
            Pl.v = *(const s16x8*)&sB[3136 + base];     // ds_read_b128
            acc2[ntt] = MFMA16(K2h[ks].v, Ph.v, acc2[ntt]);
            acc2[ntt] = MFMA16(K2l[ks].v, Ph.v, acc2[ntt]);
            acc2[ntt] = MFMA16(K2h[ks].v, Pl.v, acc2[ntt]);
        }
    }

    // ==== score writeout: direct from registers ====
    float* scp = score_out + (size_t)bh * (32 * LW);
    #pragma unroll
    for (int ntt = 0; ntt < 4; ntt++) {
        const int t = ntt * 16 + l15;
        if (t < LW) {
            #pragma unroll
            for (int r = 0; r < 4; r++) {
                const int c = wv * 16 + g4 * 4 + r;
                scp[c * LW + t] = acc2[ntt][r];
            }
        }
    }
}

// ---------------- fallback (ws too small): VALU kernel ----------------------
__global__ __launch_bounds__(256, 4) void wa_fallback_kernel(
    const float* __restrict__ q, const float* __restrict__ k,
    const float* __restrict__ mask0, const float* __restrict__ table,
    const int* __restrict__ idx,
    float* __restrict__ score_out, float* __restrict__ attn_out)
{
    __shared__ float sPf[LW * LW];
    const int lane = threadIdx.x & 63;
    const int wv   = __builtin_amdgcn_readfirstlane((int)(threadIdx.x >> 6));
    const int bh   = blockIdx.x * 4 + wv;
    const int h    = bh & 7;
    const int w    = (bh >> 3) & 63;
    const int t    = lane;
    const int tc   = (t < LW) ? t : (LW - 1);

    const float* qp = q + (size_t)bh * (32 * LW);
    const float* kp = k + (size_t)bh * (32 * LW);

    float qreg[32];
    #pragma unroll
    for (int c = 0; c < 32; c++) qreg[c] = qp[c * LW + tc];

    float S[LW];
    #pragma unroll
    for (int s = 0; s < LW; s++) S[s] = 0.f;
    #pragma unroll
    for (int c = 0; c < 32; c++) {
        #pragma unroll
        for (int s = 0; s < LW; s++)
            S[s] = fmaf(qreg[c], kp[c * LW + s], S[s]);
    }

    const float scale = 0.17677669529663687f;
    const float* mrow = mask0 + (size_t)w * (LW * LW) + tc * LW;
    const int*   irow = idx + tc * LW;
    #pragma unroll
    for (int s = 0; s < LW; s++) {
        const float bm = table[irow[s] * NH + h] + mrow[s];
        S[s] = fmaf(S[s], scale, bm);
    }

    float m = S[0];
    #pragma unroll
    for (int s = 1; s < LW; s++) m = fmaxf(m, S[s]);
    float sum = 0.f;
    #pragma unroll
    for (int s = 0; s < LW; s++) { S[s] = __expf(S[s] - m); sum += S[s]; }
    const float invs = 1.0f / sum;
    #pragma unroll
    for (int s = 0; s < LW; s++) S[s] *= invs;

    float* attn_base = attn_out + (size_t)bh * (LW * LW);
    for (int turn = 0; turn < 4; turn++) {
        __syncthreads();
        if (turn == wv) {
            if (t < LW) {
                #pragma unroll
                for (int s = 0; s < LW; s++) sPf[t * LW + s] = S[s];
            }
            #pragma unroll
            for (int it = 0; it < 38; it++) {
                const int i = it * 64 + lane;
                if (i < LW * LW) attn_base[i] = sPf[i];
            }
        }
    }

    float* sc = score_out + (size_t)bh * (32 * LW);
    #pragma unroll
    for (int c = 0; c < 32; c++) {
        float a = 0.f;
        #pragma unroll
        for (int s = 0; s < LW; s++) a = fmaf(S[s], kp[c * LW + s], a);
        if (t < LW) sc[c * LW + t] = a;
    }
}

extern "C" void kernel_launch(void* const* d_in, const int* in_sizes, int n_in,
                              void* d_out, int out_size, void* d_ws, size_t ws_size,
                              hipStream_t stream) {
    const float* q     = (const float*)d_in[0];
    const float* k     = (const float*)d_in[1];
    // d_in[2] = v, unused: reference reassigns v = k
    const float* mask  = (const float*)d_in[3];
    const float* table = (const float*)d_in[4];
    const int*   idx   = (const int*)d_in[5];

    float* score_out = (float*)d_out;
    float* attn_out  = score_out + (size_t)2048 * 256 * 49;

    const size_t NBF = (size_t)8 * 4096;     // 32768 bf16 elems
    const size_t NMF = (size_t)64 * 4096;    // 262144 bf16 elems

    if (ws_size >= (NBF + NMF) * sizeof(unsigned short)) {
        unsigned short* biasB = (unsigned short*)d_ws;
        unsigned short* maskB = biasB + NBF;
        const int tot = (int)(NBF + NMF);
        prep_frag_kernel<<<(tot + 255) / 256, 256, 0, stream>>>(
            mask, table, idx, biasB, maskB);
        wa_mfma_kernel<<<16384, 128, 0, stream>>>(
            q, k, biasB, maskB, score_out, attn_out);
    } else {
        wa_fallback_kernel<<<4096, 256, 0, stream>>>(
            q, k, mask, table, idx, score_out, attn_out);
    }
}

// Round 12
// 443.719 us; speedup vs baseline: 1.5099x; 1.0392x over previous
//
#include <hip/hip_runtime.h>
#include <hip/hip_bf16.h>
#include <math.h>

// WindowAttention: B=2048, C=256, H=8, d_k=32, wh=ww=7 -> L=49, nW=64.
// Reference reassigns v = k. Outputs: score (2048*256*49) then attn
// (2048*8*49*49), fp32, concatenated in d_out.
//
// MFMA design, R12: REQUEST-PORT theory, store side. R11 proved the
// currency is global memory instructions through the per-CU TA port:
// cutting loads 64->23 (global_load_lds staging + K-read-once) gave
// 171->~135us after five flat rounds of volume/occupancy knobs.
// This round cuts stores 48->~23:
//  - attn: flat contiguous dword stream (19 instr, 512B/instr per block)
//    reconstructed from the P hi/lo LDS planes (bf2f(hi)+bf2f(lo), the
//    R4/R5-validated readback path), replacing 32 frag-scattered stores.
//  - score: staged f32 into the pHi LDS region (dead after all P reads,
//    barrier-protected) then written with dwordx4 flat stores (~4 instr,
//    1KB/instr per wave), replacing 16 scattered stores. Score base is
//    16B-aligned per bh (6272B stride); attn (9604B stride) stays dword.
//
// Carried: global_load_lds K+Q staging, K2-from-LDS (R11); bf16
// frag-order tables (R10); exp2-fold + no-max softmax (R9/R10); lgkm-only
// barriers (R8); HW bf16 cvt (R8). Spill tripwire: WRITE >> 256MB.

#define LW 49
#define NH 8

typedef short s16x8 __attribute__((ext_vector_type(8)));
typedef float f32x4 __attribute__((ext_vector_type(4)));
typedef unsigned short u16x4 __attribute__((ext_vector_type(4)));

union Frag { s16x8 v; unsigned short u[8]; };

__device__ __forceinline__ unsigned short f2bf(float x) {
    return __builtin_bit_cast(unsigned short, __float2bfloat16(x));
}
__device__ __forceinline__ float bf2f(unsigned short h) {
    return __uint_as_float(((unsigned)h) << 16);
}
// hi = bf16(x); lo = bf16(x - hi). 3-pass MFMA (Ah*Bh + Al*Bh + Ah*Bl)
// gives ~fp32 accuracy.
__device__ __forceinline__ void split8(const float* xf, Frag& hi, Frag& lo) {
    #pragma unroll
    for (int j = 0; j < 8; j++) {
        const unsigned short hb = f2bf(xf[j]);
        hi.u[j] = hb;
        lo.u[j] = f2bf(xf[j] - bf2f(hb));
    }
}

// LDS-only barrier: does NOT drain vmcnt (global loads/stores keep flying).
__device__ __forceinline__ void lds_barrier() {
    asm volatile("s_waitcnt lgkmcnt(0)" ::: "memory");
    __builtin_amdgcn_s_barrier();
    asm volatile("" ::: "memory");
    __builtin_amdgcn_sched_barrier(0);
}
// Stage barrier: drains vmcnt too (global_load_lds lands via vmcnt).
// Placed BEFORE table loads are issued, so only staging is drained.
__device__ __forceinline__ void stage_barrier() {
    asm volatile("s_waitcnt vmcnt(0) lgkmcnt(0)" ::: "memory");
    __builtin_amdgcn_s_barrier();
    asm volatile("" ::: "memory");
    __builtin_amdgcn_sched_barrier(0);
}

__device__ __forceinline__ void load_lds16(const void* g, void* l) {
    __builtin_amdgcn_global_load_lds(
        (const __attribute__((address_space(1))) void*)g,
        (__attribute__((address_space(3))) void*)l, 16, 0, 0);
}

#define MFMA16(A, B, C) __builtin_amdgcn_mfma_f32_16x16x32_bf16((A), (B), (C), 0, 0, 0)

// ---------------- prep: bias & mask -> bf16, frag order, log2e-folded -------
__global__ __launch_bounds__(256) void prep_frag_kernel(
    const float* __restrict__ mask, const float* __restrict__ table,
    const int* __restrict__ idx,
    unsigned short* __restrict__ biasB, unsigned short* __restrict__ maskB)
{
    const int i = blockIdx.x * 256 + threadIdx.x;
    const int NBF = 8 * 4096;        // 32768
    const int NMF = 64 * 4096;       // 262144
    const float L2E = 1.4426950408889634f;
    if (i < NBF) {
        const int h = i >> 12, rem = i & 4095;
        const int gi = rem >> 8, lane = (rem >> 2) & 63, r = rem & 3;
        const int mt = gi >> 2, nt = gi & 3;
        const int t = mt * 16 + (lane >> 4) * 4 + r;
        const int s = nt * 16 + (lane & 15);
        const float v = (t < LW && s < LW)
                      ? table[idx[t * LW + s] * NH + h] * L2E : 0.f;
        biasB[i] = f2bf(v);
    } else if (i < NBF + NMF) {
        const int j = i - NBF;
        const int w2 = j >> 12, rem = j & 4095;
        const int gi = rem >> 8, lane = (rem >> 2) & 63, r = rem & 3;
        const int mt = gi >> 2, nt = gi & 3;
        const int t = mt * 16 + (lane >> 4) * 4 + r;
        const int s = nt * 16 + (lane & 15);
        const float v = (t < LW && s < LW)
                      ? mask[w2 * (LW * LW) + t * LW + s] * L2E : 0.f;
        maskB[j] = f2bf(v);
    }
}

// ---------------- main: 2 waves per (b,h) -----------------------------------
__global__ __launch_bounds__(128, 4) void wa_mfma_kernel(
    const float* __restrict__ q, const float* __restrict__ k,
    const unsigned short* __restrict__ biasB,
    const unsigned short* __restrict__ maskB,
    float* __restrict__ score_out, float* __restrict__ attn_out)
{
    // 12800 B shared buffer, three overlapping uses (barrier-protected):
    //  stage:    raw K fp32 [0,6400), raw Q fp32 [6400,12800)
    //  P planes: pHi u16 [0,6272)B, pLo u16 [6272,12544)B   (after phase 1)
    //  score:    f32 [0,6272)B                              (after phase 3)
    __shared__ __align__(16) char sRaw[12800];

    const int wv   = __builtin_amdgcn_readfirstlane((int)(threadIdx.x >> 6));
    const int bh   = blockIdx.x;
    const int h    = bh & 7;
    const int w    = (bh >> 3) & 63;
    const int tid  = (int)threadIdx.x;    // 0..127
    const int lane = tid & 63;
    const int l15  = lane & 15;
    const int g4   = lane >> 4;

    const float* qp = q + (size_t)bh * (32 * LW);
    const float* kp = k + (size_t)bh * (32 * LW);

    char* ldsK = sRaw;
    char* ldsQ = sRaw + 6400;

    // ==== stage raw K (wave0) / raw Q (wave1) via global_load_lds ====
    {
        const char* src = (wv == 0) ? (const char*)kp : (const char*)qp;
        char*       dst = (wv == 0) ? ldsK : ldsQ;
        #pragma unroll
        for (int i = 0; i < 6; i++)
            load_lds16(src + i * 1024 + lane * 16, dst + i * 1024);
        if (lane < 16) {
            // tail [6144,6400): lanes 8..15 write pad, gptr clamped in-bounds
            const int off = (lane < 8) ? lane * 16 : 112;
            load_lds16(src + 6144 + off, dst + 6144);
        }
    }

    stage_barrier();   // staging landed (both waves); tables not yet issued

    // ==== bias/mask bf16 loads (8B/lane) — fly across phase 1 ====
    u16x4 bq4[2][4], mq4[2][4];
    {
        const unsigned short* bF = biasB + (size_t)h * 4096 + lane * 4;
        const unsigned short* mF = maskB + (size_t)w * 4096 + lane * 4;
        #pragma unroll
        for (int mi = 0; mi < 2; mi++)
            #pragma unroll
            for (int nt = 0; nt < 4; nt++) {
                const int gi = (wv * 2 + mi) * 4 + nt;
                bq4[mi][nt] = *(const u16x4*)(bF + gi * 256);
                mq4[mi][nt] = *(const u16x4*)(mF + gi * 256);
            }
    }

    const float* sKf = (const float*)ldsK;
    const float* sQf = (const float*)ldsQ;

    // ==== Q frags from LDS raw ====
    Frag Qh[2], Ql[2];
    #pragma unroll
    for (int mi = 0; mi < 2; mi++) {
        const int t  = (wv * 2 + mi) * 16 + l15;
        const int tc = t < LW ? t : (LW - 1);
        float xf[8];
        #pragma unroll
        for (int j = 0; j < 8; j++) xf[j] = sQf[(g4 * 8 + j) * LW + tc];
        split8(xf, Qh[mi], Ql[mi]);
    }

    // ==== phase 1: S rows of this wave (K frags gathered per nt) ====
    f32x4 acc[2][4];
    #pragma unroll
    for (int mi = 0; mi < 2; mi++)
        #pragma unroll
        for (int nt = 0; nt < 4; nt++)
            #pragma unroll
            for (int r = 0; r < 4; r++) acc[mi][nt][r] = 0.f;

    #pragma unroll
    for (int nt = 0; nt < 4; nt++) {
        const int s  = nt * 16 + l15;
        const int sc = s < LW ? s : (LW - 1);
        float xf[8];
        #pragma unroll
        for (int j = 0; j < 8; j++) xf[j] = sKf[(g4 * 8 + j) * LW + sc];
        Frag Kh, Kl;
        split8(xf, Kh, Kl);
        #pragma unroll
        for (int mi = 0; mi < 2; mi++) {
            acc[mi][nt] = MFMA16(Qh[mi].v, Kh.v, acc[mi][nt]);
            acc[mi][nt] = MFMA16(Ql[mi].v, Kh.v, acc[mi][nt]);
            acc[mi][nt] = MFMA16(Qh[mi].v, Kl.v, acc[mi][nt]);
        }
    }

    // ==== K2 frags from the SAME raw K (before P pack overwrites it) ====
    Frag K2h[2], K2l[2];
    {
        const int c = wv * 16 + l15;                   // c < 32 always
        #pragma unroll
        for (int ks = 0; ks < 2; ks++) {
            float xf[8];
            #pragma unroll
            for (int j = 0; j < 8; j++) {
                const int s  = ks * 32 + g4 * 8 + j;
                const int sc = s < LW ? s : (LW - 1);  // P at pad s is 0
                xf[j] = sKf[c * LW + sc];
            }
            split8(xf, K2h[ks], K2l[ks]);
        }
    }

    // ==== scale2 + bias + mask (bf16 unpack); pad cols -> -1e30 ====
    const float scale2 = 0.17677669529663687f * 1.4426950408889634f;
    #pragma unroll
    for (int mi = 0; mi < 2; mi++) {
        #pragma unroll
        for (int nt = 0; nt < 4; nt++) {
            const bool pad = (nt * 16 + l15) >= LW;
            #pragma unroll
            for (int r = 0; r < 4; r++) {
                const float bm = bf2f(bq4[mi][nt][r]) + bf2f(mq4[mi][nt][r]);
                const float v2 = fmaf(acc[mi][nt][r], scale2, bm);
                acc[mi][nt][r] = pad ? -1e30f : v2;
            }
        }
    }

    // ==== softmax over s, no max-pass, native exp2 (exact transform) ====
    #pragma unroll
    for (int mi = 0; mi < 2; mi++) {
        #pragma unroll
        for (int r = 0; r < 4; r++) {
            float sm = 0.f;
            #pragma unroll
            for (int nt = 0; nt < 4; nt++) {
                const float p = __builtin_exp2f(acc[mi][nt][r]);
                acc[mi][nt][r] = p;
                sm += p;
            }
            sm += __shfl_xor(sm, 1);
            sm += __shfl_xor(sm, 2);
            sm += __shfl_xor(sm, 4);
            sm += __shfl_xor(sm, 8);
            const float inv = 1.0f / sm;
            #pragma unroll
            for (int nt = 0; nt < 4; nt++) acc[mi][nt][r] *= inv;
        }
    }

    lds_barrier();   // #2: all raw-LDS reads done (both waves); reuse for P

    // ==== pack this wave's P rows into hi/lo planes (swizzled); acc dies ====
    unsigned short* sB = (unsigned short*)sRaw;
    #pragma unroll
    for (int mi = 0; mi < 2; mi++) {
        #pragma unroll
        for (int r = 0; r < 4; r++) {
            const int t = (wv * 2 + mi) * 16 + g4 * 4 + r;
            if (t < LW) {
                #pragma unroll
                for (int nt = 0; nt < 4; nt++) {
                    const int s = nt * 16 + l15;
                    const float p = acc[mi][nt][r];
                    const unsigned short ph = f2bf(p);
                    const unsigned short pl = f2bf(p - bf2f(ph));
                    const unsigned idx = (unsigned)t * 64u
                        + ((((unsigned)s >> 3) ^ ((unsigned)t & 7u)) << 3)
                        + ((unsigned)s & 7u);
                    sB[idx]        = ph;
                    sB[3136 + idx] = pl;
                }
            }
        }
    }

    lds_barrier();   // #3: P staged (both waves)

    // ==== attn writeout: FLAT contiguous dword stream from P planes ====
    // value = bf2f(hi)+bf2f(lo) (R4/R5-validated reconstruct, err ~2^-17).
    // 19 instr/wave, 256B contiguous per wave per instr.
    float* attn_base = attn_out + (size_t)bh * (LW * LW);
    #pragma unroll
    for (int it = 0; it < 19; it++) {
        const int i = it * 128 + tid;
        if (i < LW * LW) {
            const int t = i / LW;                      // magic-mul div
            const int s = i - t * LW;
            const unsigned idx = (unsigned)t * 64u
                + ((((unsigned)s >> 3) ^ ((unsigned)t & 7u)) << 3)
                + ((unsigned)s & 7u);
            attn_base[i] = bf2f(sB[idx]) + bf2f(sB[3136 + idx]);
        }
    }

    // ==== phase 3: score(c,t) = sum_s K(c,s) P(t,s); A-frags via b128 ====
    // attn stores above overlap these MFMAs (lgkm barriers don't drain vm).
    f32x4 acc2[4];
    #pragma unroll
    for (int nt = 0; nt < 4; nt++)
        #pragma unroll
        for (int r = 0; r < 4; r++) acc2[nt][r] = 0.f;

    #pragma unroll
    for (int ntt = 0; ntt < 4; ntt++) {
        const int t  = ntt * 16 + l15;
        const int tr = t < LW ? t : (LW - 1);          // clamped dead cols
        #pragma unroll
        for (int ks = 0; ks < 2; ks++) {
            const unsigned base = (unsigned)tr * 64u
                + (((unsigned)(ks * 4 + g4) ^ ((unsigned)tr & 7u)) << 3);
            Frag Ph, Pl;
            Ph.v = *(const s16x8*)&sB[base];            // ds_read_b128
            Pl.v = *(const s16x8*)&sB[3136 + base];     // ds_read_b128
            acc2[ntt] = MFMA16(K2h[ks].v, Ph.v, acc2[ntt]);
            acc2[ntt] = MFMA16(K2l[ks].v, Ph.v, acc2[ntt]);
            acc2[ntt] = MFMA16(K2h[ks].v, Pl.v, acc2[ntt]);
        }
    }

    lds_barrier();   // #4: all P reads (attn writeout + phase 3) done

    // ==== stage score f32 into [0,6272) (pHi region, now dead) ====
    float* scf = (float*)sRaw;
    #pragma unroll
    for (int ntt = 0; ntt < 4; ntt++) {
        const int t = ntt * 16 + l15;
        if (t < LW) {
            #pragma unroll
            for (int r = 0; r < 4; r++) {
                const int c = wv * 16 + g4 * 4 + r;
                scf[c * LW + t] = acc2[ntt][r];
            }
        }
    }

    lds_barrier();   // #5: score staged (both waves)

    // ==== score writeout: flat dwordx4 (16B-aligned: 6272B bh stride) ====
    {
        float4* dst4 = (float4*)(score_out + (size_t)bh * (32 * LW));
        const float4* src4 = (const float4*)sRaw;
        #pragma unroll
        for (int k2 = 0; k2 < 4; k2++) {
            const int j = k2 * 128 + tid;
            if (j < 392) dst4[j] = src4[j];            // 392 = 6272/16
        }
    }
}

// ---------------- fallback (ws too small): VALU kernel ----------------------
__global__ __launch_bounds__(256, 4) void wa_fallback_kernel(
    const float* __restrict__ q, const float* __restrict__ k,
    const float* __restrict__ mask0, const float* __restrict__ table,
    const int* __restrict__ idx,
    float* __restrict__ score_out, float* __restrict__ attn_out)
{
    __shared__ float sPf[LW * LW];
    const int lane = threadIdx.x & 63;
    const int wv   = __builtin_amdgcn_readfirstlane((int)(threadIdx.x >> 6));
    const int bh   = blockIdx.x * 4 + wv;
    const int h    = bh & 7;
    const int w    = (bh >> 3) & 63;
    const int t    = lane;
    const int tc   = (t < LW) ? t : (LW - 1);

    const float* qp = q + (size_t)bh * (32 * LW);
    const float* kp = k + (size_t)bh * (32 * LW);

    float qreg[32];
    #pragma unroll
    for (int c = 0; c < 32; c++) qreg[c] = qp[c * LW + tc];

    float S[LW];
    #pragma unroll
    for (int s = 0; s < LW; s++) S[s] = 0.f;
    #pragma unroll
    for (int c = 0; c < 32; c++) {
        #pragma unroll
        for (int s = 0; s < LW; s++)
            S[s] = fmaf(qreg[c], kp[c * LW + s], S[s]);
    }

    const float scale = 0.17677669529663687f;
    const float* mrow = mask0 + (size_t)w * (LW * LW) + tc * LW;
    const int*   irow = idx + tc * LW;
    #pragma unroll
    for (int s = 0; s < LW; s++) {
        const float bm = table[irow[s] * NH + h] + mrow[s];
        S[s] = fmaf(S[s], scale, bm);
    }

    float m = S[0];
    #pragma unroll
    for (int s = 1; s < LW; s++) m = fmaxf(m, S[s]);
    float sum = 0.f;
    #pragma unroll
    for (int s = 0; s < LW; s++) { S[s] = __expf(S[s] - m); sum += S[s]; }
    const float invs = 1.0f / sum;
    #pragma unroll
    for (int s = 0; s < LW; s++) S[s] *= invs;

    float* attn_base = attn_out + (size_t)bh * (LW * LW);
    for (int turn = 0; turn < 4; turn++) {
        __syncthreads();
        if (turn == wv) {
            if (t < LW) {
                #pragma unroll
                for (int s = 0; s < LW; s++) sPf[t * LW + s] = S[s];
            }
            #pragma unroll
            for (int it = 0; it < 38; it++) {
                const int i = it * 64 + lane;
                if (i < LW * LW) attn_base[i] = sPf[i];
            }
        }
    }

    float* sc = score_out + (size_t)bh * (32 * LW);
    #pragma unroll
    for (int c = 0; c < 32; c++) {
        float a = 0.f;
        #pragma unroll
        for (int s = 0; s < LW; s++) a = fmaf(S[s], kp[c * LW + s], a);
        if (t < LW) sc[c * LW + t] = a;
    }
}

extern "C" void kernel_launch(void* const* d_in, const int* in_sizes, int n_in,
                              void* d_out, int out_size, void* d_ws, size_t ws_size,
                              hipStream_t stream) {
    const float* q     = (const float*)d_in[0];
    const float* k     = (const float*)d_in[1];
    // d_in[2] = v, unused: reference reassigns v = k
    const float* mask  = (const float*)d_in[3];
    const float* table = (const float*)d_in[4];
    const int*   idx   = (const int*)d_in[5];

    float* score_out = (float*)d_out;
    float* attn_out  = score_out + (size_t)2048 * 256 * 49;

    const size_t NBF = (size_t)8 * 4096;     // 32768 bf16 elems
    const size_t NMF = (size_t)64 * 4096;    // 262144 bf16 elems

    if (ws_size >= (NBF + NMF) * sizeof(unsigned short)) {
        unsigned short* biasB = (unsigned short*)d_ws;
        unsigned short* maskB = biasB + NBF;
        const int tot = (int)(NBF + NMF);
        prep_frag_kernel<<<(tot + 255) / 256, 256, 0, stream>>>(
            mask, table, idx, biasB, maskB);
        wa_mfma_kernel<<<16384, 128, 0, stream>>>(
            q, k, biasB, maskB, score_out, attn_out);
    } else {
        wa_fallback_kernel<<<4096, 256, 0, stream>>>(
            q, k, mask, table, idx, score_out, attn_out);
    }
}

// Round 13
// 442.428 us; speedup vs baseline: 1.5144x; 1.0029x over previous
//
#include <hip/hip_runtime.h>
#include <hip/hip_bf16.h>
#include <math.h>

// WindowAttention: B=2048, C=256, H=8, d_k=32, wh=ww=7 -> L=49, nW=64.
// Reference reassigns v = k. Outputs: score (2048*256*49) then attn
// (2048*8*49*49), fp32, concatenated in d_out.
//
// MFMA design, R13: REQUEST-PORT theory round 3. R11 (loads 64->23:
// -36us) and R12 (stores 48->23: -17us) established wall time tracks
// GLOBAL MEMORY INSTRUCTIONS through the per-CU TA port (~0.7-0.9us per
// instr removed). This round: ~46 -> ~22 instr/wave:
//  - TWO bh per 256-thread block (4 waves, 2x12.8KB LDS). attn regions of
//    the pair are contiguous & 8B-aligned -> combined float2 stream:
//    10 instr/block (~5/bh, was 19). score pair 16B-aligned -> float4:
//    4 instr/block (~2/bh).
//  - tables re-laid out [h][mt][lane][16] (nt x r packed, 32B/lane) so
//    each u16x8 16B load covers two nt-chunks: 8 loads/wave (was 16).
//
// Carried: global_load_lds K+Q staging + K2-from-LDS (R11), LDS-routed
// contiguous writeout (R12), bf16 frag tables (R10), exp2-fold + no-max
// softmax (R9/R10), lgkm-only barriers (R8), HW bf16 cvt (R8).
// Spill tripwire (R2-R4): WRITE >> 256MB.

#define LW 49
#define NH 8

typedef short s16x8 __attribute__((ext_vector_type(8)));
typedef float f32x4 __attribute__((ext_vector_type(4)));
typedef unsigned short u16x8 __attribute__((ext_vector_type(8)));

union Frag { s16x8 v; unsigned short u[8]; };

__device__ __forceinline__ unsigned short f2bf(float x) {
    return __builtin_bit_cast(unsigned short, __float2bfloat16(x));
}
__device__ __forceinline__ float bf2f(unsigned short h) {
    return __uint_as_float(((unsigned)h) << 16);
}
// hi = bf16(x); lo = bf16(x - hi). 3-pass MFMA (Ah*Bh + Al*Bh + Ah*Bl)
// gives ~fp32 accuracy.
__device__ __forceinline__ void split8(const float* xf, Frag& hi, Frag& lo) {
    #pragma unroll
    for (int j = 0; j < 8; j++) {
        const unsigned short hb = f2bf(xf[j]);
        hi.u[j] = hb;
        lo.u[j] = f2bf(xf[j] - bf2f(hb));
    }
}

// LDS-only barrier: does NOT drain vmcnt (global loads/stores keep flying).
__device__ __forceinline__ void lds_barrier() {
    asm volatile("s_waitcnt lgkmcnt(0)" ::: "memory");
    __builtin_amdgcn_s_barrier();
    asm volatile("" ::: "memory");
    __builtin_amdgcn_sched_barrier(0);
}
// Stage barrier: drains vmcnt too (global_load_lds lands via vmcnt).
// Placed BEFORE table loads are issued, so only staging is drained.
__device__ __forceinline__ void stage_barrier() {
    asm volatile("s_waitcnt vmcnt(0) lgkmcnt(0)" ::: "memory");
    __builtin_amdgcn_s_barrier();
    asm volatile("" ::: "memory");
    __builtin_amdgcn_sched_barrier(0);
}

__device__ __forceinline__ void load_lds16(const void* g, void* l) {
    __builtin_amdgcn_global_load_lds(
        (const __attribute__((address_space(1))) void*)g,
        (__attribute__((address_space(3))) void*)l, 16, 0, 0);
}

#define MFMA16(A, B, C) __builtin_amdgcn_mfma_f32_16x16x32_bf16((A), (B), (C), 0, 0, 0)

// ---------------- prep: bias & mask -> bf16, [x][mt][lane][nt*4+r] ----------
// Packed so one u16x8 (16B) load covers two nt-chunks. log2e-folded.
__global__ __launch_bounds__(256) void prep_frag_kernel(
    const float* __restrict__ mask, const float* __restrict__ table,
    const int* __restrict__ idx,
    unsigned short* __restrict__ biasB, unsigned short* __restrict__ maskB)
{
    const int i = blockIdx.x * 256 + threadIdx.x;
    const int NBF = 8 * 4096;        // 32768
    const int NMF = 64 * 4096;       // 262144
    const float L2E = 1.4426950408889634f;
    if (i < NBF) {
        const int h = i >> 12, rem = i & 4095;
        const int mt = rem >> 10, lane = (rem >> 4) & 63, e = rem & 15;
        const int nt = e >> 2, r = e & 3;
        const int t = mt * 16 + (lane >> 4) * 4 + r;
        const int s = nt * 16 + (lane & 15);
        const float v = (t < LW && s < LW)
                      ? table[idx[t * LW + s] * NH + h] * L2E : 0.f;
        biasB[i] = f2bf(v);
    } else if (i < NBF + NMF) {
        const int j = i - NBF;
        const int w2 = j >> 12, rem = j & 4095;
        const int mt = rem >> 10, lane = (rem >> 4) & 63, e = rem & 15;
        const int nt = e >> 2, r = e & 3;
        const int t = mt * 16 + (lane >> 4) * 4 + r;
        const int s = nt * 16 + (lane & 15);
        const float v = (t < LW && s < LW)
                      ? mask[w2 * (LW * LW) + t * LW + s] * L2E : 0.f;
        maskB[j] = f2bf(v);
    }
}

// ---------------- main: 4 waves, TWO bh per block ---------------------------
__global__ __launch_bounds__(256, 4) void wa_mfma_kernel(
    const float* __restrict__ q, const float* __restrict__ k,
    const unsigned short* __restrict__ biasB,
    const unsigned short* __restrict__ maskB,
    float* __restrict__ score_out, float* __restrict__ attn_out)
{
    // Per-bh 12800 B sub-buffer, three overlapping uses (barrier-protected):
    //  stage:    raw K fp32 [0,6400), raw Q fp32 [6400,12800)
    //  P planes: pHi u16 [0,6272)B, pLo u16 [6272,12544)B   (after phase 1)
    //  score:    f32 [0,6272)B                              (after phase 3)
    __shared__ __align__(16) char sRaw[2][12800];

    const int tid  = (int)threadIdx.x;    // 0..255
    const int wv   = __builtin_amdgcn_readfirstlane(tid >> 6);   // 0..3
    const int sub  = wv >> 1;             // which bh of the pair
    const int wvL  = wv & 1;              // role within the bh
    const int bh   = blockIdx.x * 2 + sub;
    const int h    = bh & 7;
    const int w    = (bh >> 3) & 63;
    const int lane = tid & 63;
    const int l15  = lane & 15;
    const int g4   = lane >> 4;

    const float* qp = q + (size_t)bh * (32 * LW);
    const float* kp = k + (size_t)bh * (32 * LW);

    char* ldsBase = &sRaw[sub][0];
    char* ldsK = ldsBase;
    char* ldsQ = ldsBase + 6400;

    // ==== stage raw K (wvL=0) / raw Q (wvL=1) via global_load_lds ====
    {
        const char* src = (wvL == 0) ? (const char*)kp : (const char*)qp;
        char*       dst = (wvL == 0) ? ldsK : ldsQ;
        #pragma unroll
        for (int i = 0; i < 6; i++)
            load_lds16(src + i * 1024 + lane * 16, dst + i * 1024);
        if (lane < 16) {
            // tail [6144,6400): lanes 8..15 write pad, gptr clamped in-bounds
            const int off = (lane < 8) ? lane * 16 : 112;
            load_lds16(src + 6144 + off, dst + 6144);
        }
    }

    stage_barrier();   // staging landed (all 4 waves); tables not yet issued

    // ==== bias/mask bf16 loads: u16x8 (16B), 8 instr/wave total ====
    u16x8 bq8[2][2], mq8[2][2];
    {
        const unsigned short* bF = biasB + (size_t)h * 4096;
        const unsigned short* mF = maskB + (size_t)w * 4096;
        #pragma unroll
        for (int mi = 0; mi < 2; mi++) {
            const int mt = wvL * 2 + mi;
            const u16x8* bp = (const u16x8*)(bF + mt * 1024 + lane * 16);
            const u16x8* mp = (const u16x8*)(mF + mt * 1024 + lane * 16);
            bq8[mi][0] = bp[0];
            bq8[mi][1] = bp[1];
            mq8[mi][0] = mp[0];
            mq8[mi][1] = mp[1];
        }
    }

    const float* sKf = (const float*)ldsK;
    const float* sQf = (const float*)ldsQ;

    // ==== Q frags from LDS raw ====
    Frag Qh[2], Ql[2];
    #pragma unroll
    for (int mi = 0; mi < 2; mi++) {
        const int t  = (wvL * 2 + mi) * 16 + l15;
        const int tc = t < LW ? t : (LW - 1);
        float xf[8];
        #pragma unroll
        for (int j = 0; j < 8; j++) xf[j] = sQf[(g4 * 8 + j) * LW + tc];
        split8(xf, Qh[mi], Ql[mi]);
    }

    // ==== phase 1: S rows of this wave (K frags gathered per nt) ====
    f32x4 acc[2][4];
    #pragma unroll
    for (int mi = 0; mi < 2; mi++)
        #pragma unroll
        for (int nt = 0; nt < 4; nt++)
            #pragma unroll
            for (int r = 0; r < 4; r++) acc[mi][nt][r] = 0.f;

    #pragma unroll
    for (int nt = 0; nt < 4; nt++) {
        const int s  = nt * 16 + l15;
        const int sc = s < LW ? s : (LW - 1);
        float xf[8];
        #pragma unroll
        for (int j = 0; j < 8; j++) xf[j] = sKf[(g4 * 8 + j) * LW + sc];
        Frag Kh, Kl;
        split8(xf, Kh, Kl);
        #pragma unroll
        for (int mi = 0; mi < 2; mi++) {
            acc[mi][nt] = MFMA16(Qh[mi].v, Kh.v, acc[mi][nt]);
            acc[mi][nt] = MFMA16(Ql[mi].v, Kh.v, acc[mi][nt]);
            acc[mi][nt] = MFMA16(Qh[mi].v, Kl.v, acc[mi][nt]);
        }
    }

    // ==== K2 frags from the SAME raw K (before P pack overwrites it) ====
    Frag K2h[2], K2l[2];
    {
        const int c = wvL * 16 + l15;                  // c < 32 always
        #pragma unroll
        for (int ks = 0; ks < 2; ks++) {
            float xf[8];
            #pragma unroll
            for (int j = 0; j < 8; j++) {
                const int s  = ks * 32 + g4 * 8 + j;
                const int sc = s < LW ? s : (LW - 1);  // P at pad s is 0
                xf[j] = sKf[c * LW + sc];
            }
            split8(xf, K2h[ks], K2l[ks]);
        }
    }

    // ==== scale2 + bias + mask (bf16 unpack); pad cols -> -1e30 ====
    const float scale2 = 0.17677669529663687f * 1.4426950408889634f;
    #pragma unroll
    for (int mi = 0; mi < 2; mi++) {
        #pragma unroll
        for (int nt = 0; nt < 4; nt++) {
            const bool pad = (nt * 16 + l15) >= LW;
            #pragma unroll
            for (int r = 0; r < 4; r++) {
                const float bm = bf2f(bq8[mi][nt >> 1][(nt & 1) * 4 + r])
                               + bf2f(mq8[mi][nt >> 1][(nt & 1) * 4 + r]);
                const float v2 = fmaf(acc[mi][nt][r], scale2, bm);
                acc[mi][nt][r] = pad ? -1e30f : v2;
            }
        }
    }

    // ==== softmax over s, no max-pass, native exp2 (exact transform) ====
    #pragma unroll
    for (int mi = 0; mi < 2; mi++) {
        #pragma unroll
        for (int r = 0; r < 4; r++) {
            float sm = 0.f;
            #pragma unroll
            for (int nt = 0; nt < 4; nt++) {
                const float p = __builtin_exp2f(acc[mi][nt][r]);
                acc[mi][nt][r] = p;
                sm += p;
            }
            sm += __shfl_xor(sm, 1);
            sm += __shfl_xor(sm, 2);
            sm += __shfl_xor(sm, 4);
            sm += __shfl_xor(sm, 8);
            const float inv = 1.0f / sm;
            #pragma unroll
            for (int nt = 0; nt < 4; nt++) acc[mi][nt][r] *= inv;
        }
    }

    lds_barrier();   // #2: all raw-LDS reads done; reuse sub-buffers for P

    // ==== pack this wave's P rows into hi/lo planes (swizzled); acc dies ====
    unsigned short* sB = (unsigned short*)ldsBase;
    #pragma unroll
    for (int mi = 0; mi < 2; mi++) {
        #pragma unroll
        for (int r = 0; r < 4; r++) {
            const int t = (wvL * 2 + mi) * 16 + g4 * 4 + r;
            if (t < LW) {
                #pragma unroll
                for (int nt = 0; nt < 4; nt++) {
                    const int s = nt * 16 + l15;
                    const float p = acc[mi][nt][r];
                    const unsigned short ph = f2bf(p);
                    const unsigned short pl = f2bf(p - bf2f(ph));
                    const unsigned idx = (unsigned)t * 64u
                        + ((((unsigned)s >> 3) ^ ((unsigned)t & 7u)) << 3)
                        + ((unsigned)s & 7u);
                    sB[idx]        = ph;
                    sB[3136 + idx] = pl;
                }
            }
        }
    }

    lds_barrier();   // #3: P staged for BOTH bh

    // ==== attn writeout: combined pair stream, float2 (8B-aligned) ====
    // value = bf2f(hi)+bf2f(lo) (validated reconstruct, err ~2^-17).
    // 2401 float2 slots over 256 threads = 10 instr/block (~5/bh).
    {
        float2* dst2 = (float2*)(attn_out + (size_t)(blockIdx.x * 2) * (LW * LW));
        #pragma unroll
        for (int it = 0; it < 10; it++) {
            const int j = it * 256 + tid;
            if (j < LW * LW) {                         // 2401 slots
                float v2[2];
                #pragma unroll
                for (int e = 0; e < 2; e++) {
                    const int g  = 2 * j + e;
                    const int sg = g >= LW * LW;       // which bh of pair
                    const int i2 = g - sg * (LW * LW);
                    const int t  = i2 / LW;            // magic-mul div
                    const int s  = i2 - t * LW;
                    const unsigned idx = (unsigned)t * 64u
                        + ((((unsigned)s >> 3) ^ ((unsigned)t & 7u)) << 3)
                        + ((unsigned)s & 7u);
                    const unsigned short* sBg = (const unsigned short*)&sRaw[sg][0];
                    v2[e] = bf2f(sBg[idx]) + bf2f(sBg[3136 + idx]);
                }
                dst2[j] = make_float2(v2[0], v2[1]);
            }
        }
    }

    // ==== phase 3: score(c,t) = sum_s K(c,s) P(t,s); A-frags via b128 ====
    // attn stores above overlap these MFMAs (lgkm barriers don't drain vm).
    f32x4 acc2[4];
    #pragma unroll
    for (int nt = 0; nt < 4; nt++)
        #pragma unroll
        for (int r = 0; r < 4; r++) acc2[nt][r] = 0.f;

    #pragma unroll
    for (int ntt = 0; ntt < 4; ntt++) {
        const int t  = ntt * 16 + l15;
        const int tr = t < LW ? t : (LW - 1);          // clamped dead cols
        #pragma unroll
        for (int ks = 0; ks < 2; ks++) {
            const unsigned base = (unsigned)tr * 64u
                + (((unsigned)(ks * 4 + g4) ^ ((unsigned)tr & 7u)) << 3);
            Frag Ph, Pl;
            Ph.v = *(const s16x8*)&sB[base];            // ds_read_b128
            Pl.v = *(const s16x8*)&sB[3136 + base];     // ds_read_b128
            acc2[ntt] = MFMA16(K2h[ks].v, Ph.v, acc2[ntt]);
            acc2[ntt] = MFMA16(K2l[ks].v, Ph.v, acc2[ntt]);
            acc2[ntt] = MFMA16(K2h[ks].v, Pl.v, acc2[ntt]);
        }
    }

    lds_barrier();   // #4: all P reads (attn writeout + phase 3) done

    // ==== stage score f32 into [0,6272) of own sub (pHi region, dead) ====
    float* scf = (float*)ldsBase;
    #pragma unroll
    for (int ntt = 0; ntt < 4; ntt++) {
        const int t = ntt * 16 + l15;
        if (t < LW) {
            #pragma unroll
            for (int r = 0; r < 4; r++) {
                const int c = wvL * 16 + g4 * 4 + r;
                scf[c * LW + t] = acc2[ntt][r];
            }
        }
    }

    lds_barrier();   // #5: score staged for BOTH bh

    // ==== score writeout: combined pair stream, float4 (16B-aligned) ====
    // 784 float4 slots over 256 threads = 4 instr/block (~2/bh).
    {
        float4* dst4 = (float4*)(score_out + (size_t)(blockIdx.x * 2) * (32 * LW));
        #pragma unroll
        for (int it = 0; it < 4; it++) {
            const int j = it * 256 + tid;
            if (j < 784) {                             // 2*6272B/16B
                const int sg = j >= 392;               // which bh of pair
                const float4* src4 = (const float4*)&sRaw[sg][0];
                dst4[j] = src4[j - sg * 392];
            }
        }
    }
}

// ---------------- fallback (ws too small): VALU kernel ----------------------
__global__ __launch_bounds__(256, 4) void wa_fallback_kernel(
    const float* __restrict__ q, const float* __restrict__ k,
    const float* __restrict__ mask0, const float* __restrict__ table,
    const int* __restrict__ idx,
    float* __restrict__ score_out, float* __restrict__ attn_out)
{
    __shared__ float sPf[LW * LW];
    const int lane = threadIdx.x & 63;
    const int wv   = __builtin_amdgcn_readfirstlane((int)(threadIdx.x >> 6));
    const int bh   = blockIdx.x * 4 + wv;
    const int h    = bh & 7;
    const int w    = (bh >> 3) & 63;
    const int t    = lane;
    const int tc   = (t < LW) ? t : (LW - 1);

    const float* qp = q + (size_t)bh * (32 * LW);
    const float* kp = k + (size_t)bh * (32 * LW);

    float qreg[32];
    #pragma unroll
    for (int c = 0; c < 32; c++) qreg[c] = qp[c * LW + tc];

    float S[LW];
    #pragma unroll
    for (int s = 0; s < LW; s++) S[s] = 0.f;
    #pragma unroll
    for (int c = 0; c < 32; c++) {
        #pragma unroll
        for (int s = 0; s < LW; s++)
            S[s] = fmaf(qreg[c], kp[c * LW + s], S[s]);
    }

    const float scale = 0.17677669529663687f;
    const float* mrow = mask0 + (size_t)w * (LW * LW) + tc * LW;
    const int*   irow = idx + tc * LW;
    #pragma unroll
    for (int s = 0; s < LW; s++) {
        const float bm = table[irow[s] * NH + h] + mrow[s];
        S[s] = fmaf(S[s], scale, bm);
    }

    float m = S[0];
    #pragma unroll
    for (int s = 1; s < LW; s++) m = fmaxf(m, S[s]);
    float sum = 0.f;
    #pragma unroll
    for (int s = 0; s < LW; s++) { S[s] = __expf(S[s] - m); sum += S[s]; }
    const float invs = 1.0f / sum;
    #pragma unroll
    for (int s = 0; s < LW; s++) S[s] *= invs;

    float* attn_base = attn_out + (size_t)bh * (LW * LW);
    for (int turn = 0; turn < 4; turn++) {
        __syncthreads();
        if (turn == wv) {
            if (t < LW) {
                #pragma unroll
                for (int s = 0; s < LW; s++) sPf[t * LW + s] = S[s];
            }
            #pragma unroll
            for (int it = 0; it < 38; it++) {
                const int i = it * 64 + lane;
                if (i < LW * LW) attn_base[i] = sPf[i];
            }
        }
    }

    float* sc = score_out + (size_t)bh * (32 * LW);
    #pragma unroll
    for (int c = 0; c < 32; c++) {
        float a = 0.f;
        #pragma unroll
        for (int s = 0; s < LW; s++) a = fmaf(S[s], kp[c * LW + s], a);
        if (t < LW) sc[c * LW + t] = a;
    }
}

extern "C" void kernel_launch(void* const* d_in, const int* in_sizes, int n_in,
                              void* d_out, int out_size, void* d_ws, size_t ws_size,
                              hipStream_t stream) {
    const float* q     = (const float*)d_in[0];
    const float* k     = (const float*)d_in[1];
    // d_in[2] = v, unused: reference reassigns v = k
    const float* mask  = (const float*)d_in[3];
    const float* table = (const float*)d_in[4];
    const int*   idx   = (const int*)d_in[5];

    float* score_out = (float*)d_out;
    float* attn_out  = score_out + (size_t)2048 * 256 * 49;

    const size_t NBF = (size_t)8 * 4096;     // 32768 bf16 elems
    const size_t NMF = (size_t)64 * 4096;    // 262144 bf16 elems

    if (ws_size >= (NBF + NMF) * sizeof(unsigned short)) {
        unsigned short* biasB = (unsigned short*)d_ws;
        unsigned short* maskB = biasB + NBF;
        const int tot = (int)(NBF + NMF);
        prep_frag_kernel<<<(tot + 255) / 256, 256, 0, stream>>>(
            mask, table, idx, biasB, maskB);
        wa_mfma_kernel<<<8192, 256, 0, stream>>>(
            q, k, biasB, maskB, score_out, attn_out);
    } else {
        wa_fallback_kernel<<<4096, 256, 0, stream>>>(
            q, k, mask, table, idx, score_out, attn_out);
    }
}